// Round 1
// 166.789 us; speedup vs baseline: 1.0538x; 1.0538x over previous
//
#include <hip/hip_runtime.h>

// Problem constants: B=32, T=1024, IN=1024, OUT=1024
// M = B*T = 32768, K = IN = 1024, N = OUT = 1024
#define M_DIM 32768
#define N_DIM 1024
#define K_DIM 1024
#define T_DIM 1024
#define B_DIM 32
#define NCHUNK 8
#define CHUNK_T 128   // T_DIM / NCHUNK

typedef unsigned int uint32;
typedef __attribute__((ext_vector_type(8))) short short8;       // 8 bf16 (MFMA A/B frag)
typedef __attribute__((ext_vector_type(8))) unsigned short ushort8v;
typedef __attribute__((ext_vector_type(4))) float floatx4;      // MFMA C/D frag

__device__ __forceinline__ unsigned short f2bf(float f) {
    uint32 u = __float_as_uint(f);
    uint32 r = u + 0x7fffu + ((u >> 16) & 1u);
    return (unsigned short)(r >> 16);
}

__device__ __forceinline__ float bf2f(unsigned short h) {
    return __uint_as_float(((uint32)h) << 16);
}

__device__ __forceinline__ void async_load16(const void* g, void* s) {
    __builtin_amdgcn_global_load_lds(
        (const __attribute__((address_space(1))) void*)g,
        (__attribute__((address_space(3))) void*)s,
        16, 0, 0);
}

// ---------------------------------------------------------------------------
// fp32 -> bf16 cast, 8 elems/thread (16B store)
// ---------------------------------------------------------------------------
__global__ void cast_f32_bf16_x8(const float* __restrict__ src,
                                 unsigned short* __restrict__ dst, int n8) {
    int i = blockIdx.x * blockDim.x + threadIdx.x;
    if (i < n8) {
        const float4* s4 = (const float4*)src;
        float4 v0 = s4[(size_t)i * 2];
        float4 v1 = s4[(size_t)i * 2 + 1];
        ushort8v o;
        o[0] = f2bf(v0.x); o[1] = f2bf(v0.y); o[2] = f2bf(v0.z); o[3] = f2bf(v0.w);
        o[4] = f2bf(v1.x); o[5] = f2bf(v1.y); o[6] = f2bf(v1.z); o[7] = f2bf(v1.w);
        ((ushort8v*)dst)[i] = o;
    }
}

// ---------------------------------------------------------------------------
// NEW main-path GEMM: 256x256 tile, BK=32, 4-deep LDS ring, counted vmcnt.
//
// Schedule invariants (one barrier + one vmcnt per K-tile, never vmcnt(0)):
//  - 4 LDS buffers of (A 256x32 + B 256x32) bf16 = 32KB each, 128KB total.
//  - Per K-tile each thread issues exactly 4 global_load_lds (2 A + 2 B).
//  - Iter t:  vmcnt(4)  -> tile t landed (tile t+1 still in flight)
//             s_barrier -> workgroup agrees tile t resident
//             stage tile t+2 into buf[(t+2)&3]   (last read at iter t-2,
//                 protected by the two intervening barriers)
//             2 phases of {ds_read frags ; setprio(1) ; 16 MFMA ; setprio(0)}
//  - Swizzle: LDS chunk ch holds global K-chunk ch ^ ((row>>1)&3); read side
//    uses the same involution. 16 lanes of a quad spread over 8 distinct 16B
//    slots (2-way = free), matching the proven 128x64 pattern.
// ---------------------------------------------------------------------------
__global__ __launch_bounds__(512, 2) void gemm_mfma256(
    const unsigned short* __restrict__ A,   // [M, K] bf16
    const unsigned short* __restrict__ Bw,  // [N, K] bf16
    const float* __restrict__ bias,         // [N]
    unsigned short* __restrict__ outBf) {   // [M, N] bf16
    extern __shared__ __align__(16) unsigned short smem[];  // 4 * 16384 shorts

    const int tid  = threadIdx.x;
    const int lane = tid & 63;
    const int wid  = tid >> 6;      // 0..7
    const int l15  = lane & 15;
    const int quad = lane >> 4;
    const int wm   = wid >> 2;      // 0..1  (M half: 128 rows)
    const int wn   = wid & 3;       // 0..3  (N quarter: 64 cols)

    // XCD-aware remap: 512 blocks, xcd owns M-panels [xcd*16, xcd*16+16),
    // 4 consecutive N-tiles per panel -> A-panel L2-resident per XCD.
    const int L   = blockIdx.y * gridDim.x + blockIdx.x;   // 0..511
    const int xcd = L & 7;
    const int s   = L >> 3;
    const int bn0 = (s & 3) * 256;
    const int bm0 = (xcd * 16 + (s >> 2)) * 256;

    // Per-thread staging addresses (constant except k0).
    const int row0 = tid >> 2;                 // 0..127
    const int ch   = tid & 3;
    const int sc   = ch ^ ((tid >> 3) & 3);    // == ch ^ ((row>>1)&3), both q
    const size_t aoff0 = (size_t)(bm0 + row0) * K_DIM + sc * 8;
    const size_t aoff1 = (size_t)(bm0 + 128 + row0) * K_DIM + sc * 8;
    const size_t boff0 = (size_t)(bn0 + row0) * K_DIM + sc * 8;
    const size_t boff1 = (size_t)(bn0 + 128 + row0) * K_DIM + sc * 8;
    const int ldsoff0 = (wid * 64) * 8;        // wave-uniform dest bases
    const int ldsoff1 = (512 + wid * 64) * 8;

#define ABUF(b) (smem + (b) * 16384)
#define BBUF(b) (smem + (b) * 16384 + 8192)
#define STAGE(ts, b) do {                                        \
        const int _k0 = (ts) * 32;                               \
        async_load16(A  + aoff0 + _k0, ABUF(b) + ldsoff0);       \
        async_load16(A  + aoff1 + _k0, ABUF(b) + ldsoff1);       \
        async_load16(Bw + boff0 + _k0, BBUF(b) + ldsoff0);       \
        async_load16(Bw + boff1 + _k0, BBUF(b) + ldsoff1);       \
    } while (0)

    floatx4 acc[8][4];
#pragma unroll
    for (int i = 0; i < 8; ++i)
#pragma unroll
        for (int j = 0; j < 4; ++j)
            acc[i][j] = (floatx4){0.f, 0.f, 0.f, 0.f};

    // Prologue: tiles 0 and 1 in flight.
    STAGE(0, 0);
    STAGE(1, 1);

    const int NT = K_DIM / 32;   // 32
    const int scq8 = (quad ^ ((l15 >> 1) & 3)) * 8;   // read-side swizzle

    for (int t = 0; t < NT; ++t) {
        asm volatile("s_waitcnt vmcnt(4)" ::: "memory");  // tile t landed
        __builtin_amdgcn_s_barrier();
        asm volatile("" ::: "memory");

        int ts = t + 2;
        if (ts >= NT) ts -= NT;                 // wrap: harmless re-stage
        STAGE(ts, (t + 2) & 3);

        const unsigned short* As = ABUF(t & 3);
        const unsigned short* Bs = BBUF(t & 3);

        short8 af[8], bfr[4];
#pragma unroll
        for (int i = 0; i < 4; ++i) {
            int r = wm * 128 + i * 16 + l15;
            af[i] = *(const short8*)&As[r * 32 + scq8];
        }
#pragma unroll
        for (int j = 0; j < 4; ++j) {
            int r = wn * 64 + j * 16 + l15;
            bfr[j] = *(const short8*)&Bs[r * 32 + scq8];
        }
        __builtin_amdgcn_s_setprio(1);
#pragma unroll
        for (int i = 0; i < 4; ++i)
#pragma unroll
            for (int j = 0; j < 4; ++j)
                acc[i][j] = __builtin_amdgcn_mfma_f32_16x16x32_bf16(
                    af[i], bfr[j], acc[i][j], 0, 0, 0);
        __builtin_amdgcn_s_setprio(0);

#pragma unroll
        for (int i = 4; i < 8; ++i) {
            int r = wm * 128 + i * 16 + l15;
            af[i] = *(const short8*)&As[r * 32 + scq8];
        }
        __builtin_amdgcn_s_setprio(1);
#pragma unroll
        for (int i = 4; i < 8; ++i)
#pragma unroll
            for (int j = 0; j < 4; ++j)
                acc[i][j] = __builtin_amdgcn_mfma_f32_16x16x32_bf16(
                    af[i], bfr[j], acc[i][j], 0, 0, 0);
        __builtin_amdgcn_s_setprio(0);
    }
    // Drain before exit: no in-flight LDS-DMA into a deallocated workgroup.
    asm volatile("s_waitcnt vmcnt(0)" ::: "memory");

    // Epilogue: C/D layout col = lane&15, row = quad*4 + reg (proven).
#pragma unroll
    for (int j = 0; j < 4; ++j) {
        int col = bn0 + wn * 64 + j * 16 + l15;
        float bb = bias[col];
#pragma unroll
        for (int i = 0; i < 8; ++i) {
            int rowb = bm0 + wm * 128 + i * 16 + quad * 4;
#pragma unroll
            for (int r = 0; r < 4; ++r) {
                float v = acc[i][j][r] + bb;
                outBf[(size_t)(rowb + r) * N_DIM + col] = f2bf(v);
            }
        }
    }
#undef STAGE
#undef ABUF
#undef BBUF
}

// ---------------------------------------------------------------------------
// OLD 128x128 GEMM — kept as fallback (mid path / if 128KB LDS opt-in fails)
// ---------------------------------------------------------------------------
__global__ __launch_bounds__(256) void gemm_mfma(
    const unsigned short* __restrict__ A,   // [M, K] bf16
    const unsigned short* __restrict__ Bw,  // [N, K] bf16
    const float* __restrict__ bias,         // [N]
    unsigned short* outBf,                  // [M, N] bf16 (or null)
    float* outF) {                          // [M, N] fp32 (or null)
    __shared__ unsigned short As[128 * 64];
    __shared__ unsigned short Bs[128 * 64];

    const int tid  = threadIdx.x;
    const int lane = tid & 63;
    const int wid  = tid >> 6;
    const int l15  = lane & 15;
    const int quad = lane >> 4;
    const int wm   = wid >> 1;
    const int wn   = wid & 1;

    const int L    = blockIdx.y * gridDim.x + blockIdx.x;
    const int xcd  = L & 7;
    const int s    = L >> 3;
    const int bn0  = (s & 7) * 128;
    const int bm0  = (xcd * 32 + (s >> 3)) * 128;

    floatx4 acc[4][4];
#pragma unroll
    for (int i = 0; i < 4; ++i)
#pragma unroll
        for (int j = 0; j < 4; ++j)
            acc[i][j] = (floatx4){0.f, 0.f, 0.f, 0.f};

    for (int kt = 0; kt < K_DIM / 64; ++kt) {
        const int k0 = kt * 64;
#pragma unroll
        for (int q = 0; q < 4; ++q) {
            int slot = q * 256 + tid;
            int row  = slot >> 3;
            int chq  = slot & 7;
            int scq  = chq ^ (row & 7);
            async_load16(A + (size_t)(bm0 + row) * K_DIM + k0 + scq * 8,
                         &As[(q * 256 + wid * 64) * 8]);
        }
#pragma unroll
        for (int q = 0; q < 4; ++q) {
            int slot = q * 256 + tid;
            int row  = slot >> 3;
            int chq  = slot & 7;
            int scq  = chq ^ (row & 7);
            async_load16(Bw + (size_t)(bn0 + row) * K_DIM + k0 + scq * 8,
                         &Bs[(q * 256 + wid * 64) * 8]);
        }
        __syncthreads();

#pragma unroll
        for (int ks = 0; ks < 2; ++ks) {
            short8 af[4], bfr[4];
#pragma unroll
            for (int i = 0; i < 4; ++i) {
                int r = wm * 64 + i * 16 + l15;
                int c = ks * 4 + quad;
                af[i] = *(const short8*)&As[r * 64 + ((c ^ (r & 7)) * 8)];
            }
#pragma unroll
            for (int j = 0; j < 4; ++j) {
                int r = wn * 64 + j * 16 + l15;
                int c = ks * 4 + quad;
                bfr[j] = *(const short8*)&Bs[r * 64 + ((c ^ (r & 7)) * 8)];
            }
#pragma unroll
            for (int i = 0; i < 4; ++i)
#pragma unroll
                for (int j = 0; j < 4; ++j)
                    acc[i][j] = __builtin_amdgcn_mfma_f32_16x16x32_bf16(
                        af[i], bfr[j], acc[i][j], 0, 0, 0);
        }
        __syncthreads();
    }

#pragma unroll
    for (int j = 0; j < 4; ++j) {
        int col = bn0 + wn * 64 + j * 16 + l15;
        float bb = bias[col];
#pragma unroll
        for (int i = 0; i < 4; ++i) {
            int rowb = bm0 + wm * 64 + i * 16 + quad * 4;
#pragma unroll
            for (int r = 0; r < 4; ++r) {
                float v = acc[i][j][r] + bb;
                size_t idx = (size_t)(rowb + r) * N_DIM + col;
                if (outBf) outBf[idx] = f2bf(v);
                else       outF[idx]  = v;
            }
        }
    }
}

// ---------------------------------------------------------------------------
// Reduce-then-scan over T, 2-wide over o (dword = 2 bf16), unroll 32.
// ---------------------------------------------------------------------------
__global__ __launch_bounds__(256) void scan_carry2(
    const uint32* __restrict__ cur32,         // [M, N/2] (bf16 pairs)
    const float* __restrict__ decay,
    float* __restrict__ carry) {              // [B, NCHUNK, N]
    int tid   = blockIdx.x * 256 + threadIdx.x;   // 0 .. 131071
    int o2    = tid & 511;
    int chunk = (tid >> 9) & (NCHUNK - 1);
    int b     = tid >> 12;
    int o     = o2 * 2;
    size_t base = ((size_t)b * T_DIM + (size_t)chunk * CHUNK_T) * (N_DIM / 2) + o2;
    float2 a2 = *(const float2*)&decay[o];
    float a0 = a2.x, a1 = a2.y;
    float c0 = 1.f - a0, c1 = 1.f - a1;
    float u0 = 0.f, u1 = 0.f;
    for (int t0 = 0; t0 < CHUNK_T; t0 += 32) {
        uint32 x[32];
#pragma unroll
        for (int k = 0; k < 32; ++k)
            x[k] = cur32[base + (size_t)(t0 + k) * (N_DIM / 2)];
#pragma unroll
        for (int k = 0; k < 32; ++k) {
            float lo = __uint_as_float(x[k] << 16);
            float hi = __uint_as_float(x[k] & 0xffff0000u);
            u0 = a0 * u0 + c0 * lo;
            u1 = a1 * u1 + c1 * hi;
        }
    }
    float2* cw = (float2*)&carry[((size_t)b * NCHUNK + chunk) * N_DIM + o];
    *cw = (float2){u0, u1};
}

__global__ __launch_bounds__(256) void scan_apply2(
    const uint32* __restrict__ cur32,         // [M, N/2] (bf16 pairs)
    const float* __restrict__ decay,
    const float* __restrict__ carry,          // [B, NCHUNK, N]
    float* __restrict__ out) {                // [M, N] fp32
    int tid   = blockIdx.x * 256 + threadIdx.x;
    int o2    = tid & 511;
    int chunk = (tid >> 9) & (NCHUNK - 1);
    int b     = tid >> 12;
    int o     = o2 * 2;
    size_t base = ((size_t)b * T_DIM + (size_t)chunk * CHUNK_T) * (N_DIM / 2) + o2;
    float2 a2 = *(const float2*)&decay[o];
    float a0 = a2.x, a1 = a2.y;
    float c0 = 1.f - a0, c1 = 1.f - a1;

    float A0 = a0, A1 = a1;
#pragma unroll
    for (int i = 0; i < 7; ++i) { A0 *= A0; A1 *= A1; }   // a^128

    float u0 = 0.f, u1 = 0.f;
    const float* cb = carry + (size_t)b * NCHUNK * N_DIM + o;
    for (int i = 0; i < chunk; ++i) {         // wave-uniform trip count
        float2 cv = *(const float2*)&cb[(size_t)i * N_DIM];
        u0 = cv.x + A0 * u0;
        u1 = cv.y + A1 * u1;
    }

    float2* out2 = (float2*)out;
    size_t obase = ((size_t)b * T_DIM + (size_t)chunk * CHUNK_T) * (N_DIM / 2) + o2;
    for (int t0 = 0; t0 < CHUNK_T; t0 += 32) {
        uint32 x[32];
#pragma unroll
        for (int k = 0; k < 32; ++k)
            x[k] = cur32[base + (size_t)(t0 + k) * (N_DIM / 2)];
#pragma unroll
        for (int k = 0; k < 32; ++k) {
            float lo = __uint_as_float(x[k] << 16);
            float hi = __uint_as_float(x[k] & 0xffff0000u);
            u0 = a0 * u0 + c0 * lo;
            u1 = a1 * u1 + c1 * hi;
            out2[obase + (size_t)(t0 + k) * (N_DIM / 2)] = (float2){u0, u1};
        }
    }
}

// ---------------------------------------------------------------------------
// Fallbacks (only used if workspace too small for the bf16 path)
// ---------------------------------------------------------------------------
__global__ void scan_f32_inplace(float* __restrict__ buf,
                                 const float* __restrict__ decay) {
    int tid = blockIdx.x * 64 + threadIdx.x;
    int o = tid & (N_DIM - 1);
    size_t base = ((size_t)(tid >> 10) << 20) + o;
    float a = decay[o];
    float c = 1.f - a;
    float u = 0.f;
    for (int t0 = 0; t0 < 1024; t0 += 16) {
        float x[16];
#pragma unroll
        for (int k = 0; k < 16; ++k)
            x[k] = buf[base + (size_t)(t0 + k) * N_DIM];
#pragma unroll
        for (int k = 0; k < 16; ++k) {
            u = a * u + c * x[k];
            buf[base + (size_t)(t0 + k) * N_DIM] = u;
        }
    }
}

__global__ void gemm_naive(const float* __restrict__ X, const float* __restrict__ W,
                           const float* __restrict__ bias, float* __restrict__ out) {
    __shared__ float As[16][17], Bs[16][17];
    int tx = threadIdx.x, ty = threadIdx.y;
    int m0 = blockIdx.y * 16, n0 = blockIdx.x * 16;
    float acc = 0.f;
    for (int k0 = 0; k0 < K_DIM; k0 += 16) {
        As[ty][tx] = X[(size_t)(m0 + ty) * K_DIM + k0 + tx];
        Bs[ty][tx] = W[(size_t)(n0 + ty) * K_DIM + k0 + tx];
        __syncthreads();
#pragma unroll
        for (int kk = 0; kk < 16; ++kk) acc += As[ty][kk] * Bs[tx][kk];
        __syncthreads();
    }
    out[(size_t)(m0 + ty) * N_DIM + n0 + tx] = acc + bias[n0 + tx];
}

// ---------------------------------------------------------------------------
extern "C" void kernel_launch(void* const* d_in, const int* in_sizes, int n_in,
                              void* d_out, int out_size, void* d_ws, size_t ws_size,
                              hipStream_t stream) {
    const float* X     = (const float*)d_in[0];  // [B,T,IN]  = [M,K]
    const float* Wt    = (const float*)d_in[1];  // [OUT,IN]  = [N,K]
    const float* bias  = (const float*)d_in[2];  // [OUT]
    const float* decay = (const float*)d_in[3];  // [OUT]
    float* out = (float*)d_out;                  // [B,T,OUT] = [M,N]

    // One-time opt-in for 128 KiB dynamic LDS (host-side, capture-safe).
    static bool big_lds_ok = [] {
        return hipFuncSetAttribute(reinterpret_cast<const void*>(gemm_mfma256),
                                   hipFuncAttributeMaxDynamicSharedMemorySize,
                                   131072) == hipSuccess;
    }();

    const size_t A_bytes  = (size_t)M_DIM * K_DIM * 2;            // 64 MB
    const size_t W_bytes  = (size_t)N_DIM * K_DIM * 2;            // 2 MB
    const size_t C_bytes  = (size_t)M_DIM * N_DIM * 2;            // 64 MB
    const size_t cr_bytes = (size_t)B_DIM * NCHUNK * N_DIM * 4;   // 1 MB
    const size_t need_mid  = A_bytes + W_bytes;
    const size_t need_full = A_bytes + W_bytes + C_bytes + cr_bytes;

    if (ws_size >= need_full) {
        unsigned short* Abf = (unsigned short*)d_ws;
        unsigned short* Wbf = (unsigned short*)((char*)d_ws + A_bytes);
        unsigned short* Cbf = (unsigned short*)((char*)d_ws + A_bytes + W_bytes);
        float* carry = (float*)((char*)d_ws + A_bytes + W_bytes + C_bytes);
        cast_f32_bf16_x8<<<(M_DIM * K_DIM / 8 + 255) / 256, 256, 0, stream>>>(X, Abf, M_DIM * K_DIM / 8);
        cast_f32_bf16_x8<<<(N_DIM * K_DIM / 8 + 255) / 256, 256, 0, stream>>>(Wt, Wbf, N_DIM * K_DIM / 8);
        if (big_lds_ok) {
            gemm_mfma256<<<dim3(4, 128), 512, 131072, stream>>>(Abf, Wbf, bias, Cbf);
        } else {
            gemm_mfma<<<dim3(N_DIM / 128, M_DIM / 128), 256, 0, stream>>>(Abf, Wbf, bias, Cbf, nullptr);
        }
        const int scan_threads = B_DIM * NCHUNK * N_DIM / 2;      // 131072
        scan_carry2<<<scan_threads / 256, 256, 0, stream>>>((const uint32*)Cbf, decay, carry);
        scan_apply2<<<scan_threads / 256, 256, 0, stream>>>((const uint32*)Cbf, decay, carry, out);
    } else if (ws_size >= need_mid) {
        unsigned short* Abf = (unsigned short*)d_ws;
        unsigned short* Wbf = (unsigned short*)((char*)d_ws + A_bytes);
        cast_f32_bf16_x8<<<(M_DIM * K_DIM / 8 + 255) / 256, 256, 0, stream>>>(X, Abf, M_DIM * K_DIM / 8);
        cast_f32_bf16_x8<<<(N_DIM * K_DIM / 8 + 255) / 256, 256, 0, stream>>>(Wt, Wbf, N_DIM * K_DIM / 8);
        gemm_mfma<<<dim3(N_DIM / 128, M_DIM / 128), 256, 0, stream>>>(Abf, Wbf, bias, nullptr, out);
        scan_f32_inplace<<<512, 64, 0, stream>>>(out, decay);
    } else {
        gemm_naive<<<dim3(N_DIM / 16, M_DIM / 16), dim3(16, 16), 0, stream>>>(X, Wt, bias, out);
        scan_f32_inplace<<<512, 64, 0, stream>>>(out, decay);
    }
}

// Round 2
// 154.926 us; speedup vs baseline: 1.1345x; 1.0766x over previous
//
#include <hip/hip_runtime.h>

// Problem constants: B=32, T=1024, IN=1024, OUT=1024
// M = B*T = 32768, K = IN = 1024, N = OUT = 1024
#define M_DIM 32768
#define N_DIM 1024
#define K_DIM 1024
#define T_DIM 1024
#define B_DIM 32
#define NCHUNK 8
#define CHUNK_T 128   // T_DIM / NCHUNK

typedef unsigned int uint32;
typedef __attribute__((ext_vector_type(8))) short short8;       // 8 bf16 (MFMA A/B frag)
typedef __attribute__((ext_vector_type(8))) unsigned short ushort8v;
typedef __attribute__((ext_vector_type(4))) float floatx4;      // MFMA C/D frag

__device__ __forceinline__ unsigned short f2bf(float f) {
    uint32 u = __float_as_uint(f);
    uint32 r = u + 0x7fffu + ((u >> 16) & 1u);
    return (unsigned short)(r >> 16);
}

__device__ __forceinline__ void async_load16(const void* g, void* s) {
    __builtin_amdgcn_global_load_lds(
        (const __attribute__((address_space(1))) void*)g,
        (__attribute__((address_space(3))) void*)s,
        16, 0, 0);
}

// ---------------------------------------------------------------------------
// fp32 -> bf16 cast, 8 elems/thread (16B store)
// ---------------------------------------------------------------------------
__global__ void cast_f32_bf16_x8(const float* __restrict__ src,
                                 unsigned short* __restrict__ dst, int n8) {
    int i = blockIdx.x * blockDim.x + threadIdx.x;
    if (i < n8) {
        const float4* s4 = (const float4*)src;
        float4 v0 = s4[(size_t)i * 2];
        float4 v1 = s4[(size_t)i * 2 + 1];
        ushort8v o;
        o[0] = f2bf(v0.x); o[1] = f2bf(v0.y); o[2] = f2bf(v0.z); o[3] = f2bf(v0.w);
        o[4] = f2bf(v1.x); o[5] = f2bf(v1.y); o[6] = f2bf(v1.z); o[7] = f2bf(v1.w);
        ((ushort8v*)dst)[i] = o;
    }
}

// ---------------------------------------------------------------------------
// 8-phase GEMM: 256x256 tile, BK=64, 2 LDS buffers, half-tile interleaved
// staging, counted vmcnt(6), two barriers per phase (m201 template).
//
// K-tile g = 4 phases p0..p3 (quadrants (ih,jh) = 00,01,10,11), 16 MFMA each.
// ds_reads per phase: p0: A-ih0(8)+B-jh0(4); p1: B-jh1(4); p2: A-ih1(8); p3: 0.
// Stage plan (1 half-tile = 2 global_load_lds per phase):
//   p0(g): A-ih1(g+1) -> buf[(g+1)&1]   (region free: last read p2(g-1))
//   p1(g): A-ih0(g+2) -> buf[g&1]       (free after p0(g))
//   p2(g): B-jh1(g+2) -> buf[g&1]       (free after p1(g))
//   p3(g): B-jh0(g+2) -> buf[g&1]       (free after p0(g))
// vmcnt(6) at p3(g), AFTER its stage, BEFORE barrier1: drains through
// p0(g)'s unit => all 4 half-tiles of tile g+1 resident; barrier publishes.
// Outstanding = units from p1,p2,p3(g) = 6 loads (never drains to 0).
// Tail: p3(NT-2) uses vmcnt(0) (no newer units exist to push the count).
// ---------------------------------------------------------------------------
__global__ __launch_bounds__(512, 2) void gemm_8phase(
    const unsigned short* __restrict__ A,   // [M, K] bf16
    const unsigned short* __restrict__ Bw,  // [N, K] bf16
    const float* __restrict__ bias,         // [N]
    unsigned short* __restrict__ outBf) {   // [M, N] bf16
    extern __shared__ __align__(16) unsigned short smem[];  // 131072 B
    // buf b: A at elem b*32768 (A[256][64]), B at b*32768+16384 (B[256][64])

    const int tid  = threadIdx.x;
    const int lane = tid & 63;
    const int wid  = tid >> 6;      // 0..7
    const int l15  = lane & 15;
    const int quad = lane >> 4;
    const int wm   = wid >> 2;      // 0..1  (M half: 128 rows)
    const int wn   = wid & 3;       // 0..3  (N quarter: 64 cols)

    // XCD-aware remap: 512 blocks; xcd owns 16 M-panels, 4 N-tiles each.
    const int L   = blockIdx.y * gridDim.x + blockIdx.x;   // 0..511
    const int xcd = L & 7;
    const int s   = L >> 3;
    const int bn0 = (s & 3) * 256;
    const int bm0 = (xcd * 16 + (s >> 2)) * 256;

    // Staging address components (per-thread). All row offsets are multiples
    // of 8, so the XOR-swizzle key (row&7) == (tid>>3)&7 for every unit.
    const int t3  = tid >> 3;                               // 0..63
    const int sc8 = ((tid & 7) ^ (t3 & 7)) * 8;             // swizzled k-chunk

    // A half-tile IH of tile T -> buf PB. rows: q*128 + IH*64 + t3
#define STAGE_A(IH, T, PB) do {                                              \
        size_t kof_ = (size_t)(T) * 64 + sc8;                                \
        _Pragma("unroll") for (int q_ = 0; q_ < 2; ++q_) {                   \
            int ar_ = q_ * 128 + (IH) * 64 + t3;                             \
            int dr_ = q_ * 128 + (IH) * 64 + wid * 8;                        \
            async_load16(A + (size_t)(bm0 + ar_) * K_DIM + kof_,             \
                         smem + (PB) * 32768 + dr_ * 64);                    \
        } } while (0)
    // B half-tile JH (rows (stripe)*64 + JH*32 + within) of tile T -> buf PB
#define STAGE_B(JH, T, PB) do {                                              \
        size_t kof_ = (size_t)(T) * 64 + sc8;                                \
        _Pragma("unroll") for (int q_ = 0; q_ < 2; ++q_) {                   \
            int br_ = (q_ * 2 + (tid >> 8)) * 64 + (JH) * 32 + (t3 & 31);    \
            int dr_ = (q_ * 2 + (wid >> 2)) * 64 + (JH) * 32 + (wid & 3) * 8;\
            async_load16(Bw + (size_t)(bn0 + br_) * K_DIM + kof_,            \
                         smem + (PB) * 32768 + 16384 + dr_ * 64);            \
        } } while (0)

#define LD_A(IH) do {                                                        \
        const unsigned short* As_ = smem + pb * 32768;                       \
        _Pragma("unroll") for (int ii = 0; ii < 4; ++ii) {                   \
            int r_ = wm * 128 + (IH) * 64 + ii * 16 + l15;                   \
            _Pragma("unroll") for (int ks = 0; ks < 2; ++ks) {               \
                int c_ = ks * 4 + quad;                                      \
                af[ii][ks] = *(const short8*)&As_[r_ * 64 +                  \
                                                 ((c_ ^ (l15 & 7)) * 8)];    \
            } } } while (0)
#define LD_B(JH) do {                                                        \
        const unsigned short* Bs_ = smem + pb * 32768 + 16384;               \
        _Pragma("unroll") for (int jj = 0; jj < 2; ++jj) {                   \
            int r_ = wn * 64 + ((JH) * 2 + jj) * 16 + l15;                   \
            _Pragma("unroll") for (int ks = 0; ks < 2; ++ks) {               \
                int c_ = ks * 4 + quad;                                      \
                bfr[(JH) * 2 + jj][ks] = *(const short8*)&Bs_[r_ * 64 +      \
                                                 ((c_ ^ (l15 & 7)) * 8)];    \
            } } } while (0)
#define MM(IH, JH) do {                                                      \
        __builtin_amdgcn_s_setprio(1);                                       \
        _Pragma("unroll") for (int ii = 0; ii < 4; ++ii)                     \
        _Pragma("unroll") for (int jj = 0; jj < 2; ++jj)                     \
        _Pragma("unroll") for (int ks = 0; ks < 2; ++ks)                     \
            acc[(IH) * 4 + ii][(JH) * 2 + jj] =                              \
                __builtin_amdgcn_mfma_f32_16x16x32_bf16(                     \
                    af[ii][ks], bfr[(JH) * 2 + jj][ks],                      \
                    acc[(IH) * 4 + ii][(JH) * 2 + jj], 0, 0, 0);             \
        __builtin_amdgcn_s_setprio(0);                                       \
    } while (0)

#define FENCE  asm volatile("" ::: "memory")
#define BAR    __builtin_amdgcn_s_barrier()
#define LGKM0  asm volatile("s_waitcnt lgkmcnt(0)" ::: "memory")
#define SCHED0 __builtin_amdgcn_sched_barrier(0)

    floatx4 acc[8][4];
#pragma unroll
    for (int i = 0; i < 8; ++i)
#pragma unroll
        for (int j = 0; j < 4; ++j)
            acc[i][j] = (floatx4){0.f, 0.f, 0.f, 0.f};

    short8 af[4][2];    // current i-half A frags
    short8 bfr[4][2];   // all 4 j B frags (jh0 loaded p0, jh1 loaded p1)

    const int NT = K_DIM / 64;   // 16

    // Prologue: tile 0 complete + 3 lead units of tile 1 (matches steady state)
    STAGE_A(0, 0, 0); STAGE_A(1, 0, 0); STAGE_B(0, 0, 0); STAGE_B(1, 0, 0);
    STAGE_A(0, 1, 1); STAGE_B(1, 1, 1); STAGE_B(0, 1, 1);
    asm volatile("s_waitcnt vmcnt(6)" ::: "memory");   // tile 0 resident
    FENCE; BAR;

    for (int g = 0; g < NT; ++g) {
        const int pb = g & 1;
        const int po = pb ^ 1;

        // ---- p0: quadrant (ih0, jh0) ----
        LD_A(0); LD_B(0);
        if (g + 1 < NT) STAGE_A(1, g + 1, po);          // A-ih1(g+1)
        FENCE; BAR; LGKM0; SCHED0;
        MM(0, 0);
        SCHED0; FENCE; BAR;

        // ---- p1: quadrant (ih0, jh1) ----
        LD_B(1);
        if (g + 2 < NT) STAGE_A(0, g + 2, pb);          // A-ih0(g+2)
        FENCE; BAR; LGKM0; SCHED0;
        MM(0, 1);
        SCHED0; FENCE; BAR;

        // ---- p2: quadrant (ih1, jh0) ----
        LD_A(1);
        if (g + 2 < NT) STAGE_B(1, g + 2, pb);          // B-jh1(g+2)
        FENCE; BAR; LGKM0; SCHED0;
        MM(1, 0);
        SCHED0; FENCE; BAR;

        // ---- p3: quadrant (ih1, jh1) ----
        if (g + 2 < NT) STAGE_B(0, g + 2, pb);          // B-jh0(g+2)
        if (g < NT - 2) {
            asm volatile("s_waitcnt vmcnt(6)" ::: "memory");  // tile g+1 ready
        } else if (g == NT - 2) {
            asm volatile("s_waitcnt vmcnt(0)" ::: "memory");  // tail drain
        }
        FENCE; BAR; LGKM0; SCHED0;
        MM(1, 1);
        SCHED0; FENCE; BAR;
    }
    asm volatile("s_waitcnt vmcnt(0)" ::: "memory");    // no-op safety drain

    // Epilogue: C/D layout col = lane&15, row = quad*4 + reg.
    // j INNERMOST: the 4x32B pieces of each 128B C-line issue back-to-back
    // so L2 merges them into fully-dirty lines (fixes 2.2x write amplification).
    float bb[4];
#pragma unroll
    for (int j = 0; j < 4; ++j) bb[j] = bias[bn0 + wn * 64 + j * 16 + l15];
#pragma unroll
    for (int i = 0; i < 8; ++i) {
        int rowb = bm0 + wm * 128 + i * 16 + quad * 4;
#pragma unroll
        for (int r = 0; r < 4; ++r) {
            size_t rb = (size_t)(rowb + r) * N_DIM + bn0 + wn * 64 + l15;
#pragma unroll
            for (int j = 0; j < 4; ++j)
                outBf[rb + j * 16] = f2bf(acc[i][j][r] + bb[j]);
        }
    }
#undef STAGE_A
#undef STAGE_B
#undef LD_A
#undef LD_B
#undef MM
#undef FENCE
#undef BAR
#undef LGKM0
#undef SCHED0
}

// ---------------------------------------------------------------------------
// OLD 128x128 GEMM — fallback (mid path / if 128KB LDS opt-in fails)
// ---------------------------------------------------------------------------
__global__ __launch_bounds__(256) void gemm_mfma(
    const unsigned short* __restrict__ A,   // [M, K] bf16
    const unsigned short* __restrict__ Bw,  // [N, K] bf16
    const float* __restrict__ bias,         // [N]
    unsigned short* outBf,                  // [M, N] bf16 (or null)
    float* outF) {                          // [M, N] fp32 (or null)
    __shared__ unsigned short As[128 * 64];
    __shared__ unsigned short Bs[128 * 64];

    const int tid  = threadIdx.x;
    const int lane = tid & 63;
    const int wid  = tid >> 6;
    const int l15  = lane & 15;
    const int quad = lane >> 4;
    const int wm   = wid >> 1;
    const int wn   = wid & 1;

    const int L    = blockIdx.y * gridDim.x + blockIdx.x;
    const int xcd  = L & 7;
    const int s    = L >> 3;
    const int bn0  = (s & 7) * 128;
    const int bm0  = (xcd * 32 + (s >> 3)) * 128;

    floatx4 acc[4][4];
#pragma unroll
    for (int i = 0; i < 4; ++i)
#pragma unroll
        for (int j = 0; j < 4; ++j)
            acc[i][j] = (floatx4){0.f, 0.f, 0.f, 0.f};

    for (int kt = 0; kt < K_DIM / 64; ++kt) {
        const int k0 = kt * 64;
#pragma unroll
        for (int q = 0; q < 4; ++q) {
            int slot = q * 256 + tid;
            int row  = slot >> 3;
            int chq  = slot & 7;
            int scq  = chq ^ (row & 7);
            async_load16(A + (size_t)(bm0 + row) * K_DIM + k0 + scq * 8,
                         &As[(q * 256 + wid * 64) * 8]);
        }
#pragma unroll
        for (int q = 0; q < 4; ++q) {
            int slot = q * 256 + tid;
            int row  = slot >> 3;
            int chq  = slot & 7;
            int scq  = chq ^ (row & 7);
            async_load16(Bw + (size_t)(bn0 + row) * K_DIM + k0 + scq * 8,
                         &Bs[(q * 256 + wid * 64) * 8]);
        }
        __syncthreads();

#pragma unroll
        for (int ks = 0; ks < 2; ++ks) {
            short8 af[4], bfr[4];
#pragma unroll
            for (int i = 0; i < 4; ++i) {
                int r = wm * 64 + i * 16 + l15;
                int c = ks * 4 + quad;
                af[i] = *(const short8*)&As[r * 64 + ((c ^ (r & 7)) * 8)];
            }
#pragma unroll
            for (int j = 0; j < 4; ++j) {
                int r = wn * 64 + j * 16 + l15;
                int c = ks * 4 + quad;
                bfr[j] = *(const short8*)&Bs[r * 64 + ((c ^ (r & 7)) * 8)];
            }
#pragma unroll
            for (int i = 0; i < 4; ++i)
#pragma unroll
                for (int j = 0; j < 4; ++j)
                    acc[i][j] = __builtin_amdgcn_mfma_f32_16x16x32_bf16(
                        af[i], bfr[j], acc[i][j], 0, 0, 0);
        }
        __syncthreads();
    }

#pragma unroll
    for (int j = 0; j < 4; ++j) {
        int col = bn0 + wn * 64 + j * 16 + l15;
        float bb = bias[col];
#pragma unroll
        for (int i = 0; i < 4; ++i) {
            int rowb = bm0 + wm * 64 + i * 16 + quad * 4;
#pragma unroll
            for (int r = 0; r < 4; ++r) {
                float v = acc[i][j][r] + bb;
                size_t idx = (size_t)(rowb + r) * N_DIM + col;
                if (outBf) outBf[idx] = f2bf(v);
                else       outF[idx]  = v;
            }
        }
    }
}

// ---------------------------------------------------------------------------
// Reduce-then-scan over T, 2-wide over o (dword = 2 bf16), unroll 32.
// ---------------------------------------------------------------------------
__global__ __launch_bounds__(256) void scan_carry2(
    const uint32* __restrict__ cur32,         // [M, N/2] (bf16 pairs)
    const float* __restrict__ decay,
    float* __restrict__ carry) {              // [B, NCHUNK, N]
    int tid   = blockIdx.x * 256 + threadIdx.x;   // 0 .. 131071
    int o2    = tid & 511;
    int chunk = (tid >> 9) & (NCHUNK - 1);
    int b     = tid >> 12;
    int o     = o2 * 2;
    size_t base = ((size_t)b * T_DIM + (size_t)chunk * CHUNK_T) * (N_DIM / 2) + o2;
    float2 a2 = *(const float2*)&decay[o];
    float a0 = a2.x, a1 = a2.y;
    float c0 = 1.f - a0, c1 = 1.f - a1;
    float u0 = 0.f, u1 = 0.f;
    for (int t0 = 0; t0 < CHUNK_T; t0 += 32) {
        uint32 x[32];
#pragma unroll
        for (int k = 0; k < 32; ++k)
            x[k] = cur32[base + (size_t)(t0 + k) * (N_DIM / 2)];
#pragma unroll
        for (int k = 0; k < 32; ++k) {
            float lo = __uint_as_float(x[k] << 16);
            float hi = __uint_as_float(x[k] & 0xffff0000u);
            u0 = a0 * u0 + c0 * lo;
            u1 = a1 * u1 + c1 * hi;
        }
    }
    float2* cw = (float2*)&carry[((size_t)b * NCHUNK + chunk) * N_DIM + o];
    *cw = (float2){u0, u1};
}

__global__ __launch_bounds__(256) void scan_apply2(
    const uint32* __restrict__ cur32,         // [M, N/2] (bf16 pairs)
    const float* __restrict__ decay,
    const float* __restrict__ carry,          // [B, NCHUNK, N]
    float* __restrict__ out) {                // [M, N] fp32
    int tid   = blockIdx.x * 256 + threadIdx.x;
    int o2    = tid & 511;
    int chunk = (tid >> 9) & (NCHUNK - 1);
    int b     = tid >> 12;
    int o     = o2 * 2;
    size_t base = ((size_t)b * T_DIM + (size_t)chunk * CHUNK_T) * (N_DIM / 2) + o2;
    float2 a2 = *(const float2*)&decay[o];
    float a0 = a2.x, a1 = a2.y;
    float c0 = 1.f - a0, c1 = 1.f - a1;

    float A0 = a0, A1 = a1;
#pragma unroll
    for (int i = 0; i < 7; ++i) { A0 *= A0; A1 *= A1; }   // a^128

    float u0 = 0.f, u1 = 0.f;
    const float* cb = carry + (size_t)b * NCHUNK * N_DIM + o;
    for (int i = 0; i < chunk; ++i) {         // wave-uniform trip count
        float2 cv = *(const float2*)&cb[(size_t)i * N_DIM];
        u0 = cv.x + A0 * u0;
        u1 = cv.y + A1 * u1;
    }

    float2* out2 = (float2*)out;
    size_t obase = ((size_t)b * T_DIM + (size_t)chunk * CHUNK_T) * (N_DIM / 2) + o2;
    for (int t0 = 0; t0 < CHUNK_T; t0 += 32) {
        uint32 x[32];
#pragma unroll
        for (int k = 0; k < 32; ++k)
            x[k] = cur32[base + (size_t)(t0 + k) * (N_DIM / 2)];
#pragma unroll
        for (int k = 0; k < 32; ++k) {
            float lo = __uint_as_float(x[k] << 16);
            float hi = __uint_as_float(x[k] & 0xffff0000u);
            u0 = a0 * u0 + c0 * lo;
            u1 = a1 * u1 + c1 * hi;
            out2[obase + (size_t)(t0 + k) * (N_DIM / 2)] = (float2){u0, u1};
        }
    }
}

// ---------------------------------------------------------------------------
// Fallbacks (only used if workspace too small for the bf16 path)
// ---------------------------------------------------------------------------
__global__ void scan_f32_inplace(float* __restrict__ buf,
                                 const float* __restrict__ decay) {
    int tid = blockIdx.x * 64 + threadIdx.x;
    int o = tid & (N_DIM - 1);
    size_t base = ((size_t)(tid >> 10) << 20) + o;
    float a = decay[o];
    float c = 1.f - a;
    float u = 0.f;
    for (int t0 = 0; t0 < 1024; t0 += 16) {
        float x[16];
#pragma unroll
        for (int k = 0; k < 16; ++k)
            x[k] = buf[base + (size_t)(t0 + k) * N_DIM];
#pragma unroll
        for (int k = 0; k < 16; ++k) {
            u = a * u + c * x[k];
            buf[base + (size_t)(t0 + k) * N_DIM] = u;
        }
    }
}

__global__ void gemm_naive(const float* __restrict__ X, const float* __restrict__ W,
                           const float* __restrict__ bias, float* __restrict__ out) {
    __shared__ float As[16][17], Bs[16][17];
    int tx = threadIdx.x, ty = threadIdx.y;
    int m0 = blockIdx.y * 16, n0 = blockIdx.x * 16;
    float acc = 0.f;
    for (int k0 = 0; k0 < K_DIM; k0 += 16) {
        As[ty][tx] = X[(size_t)(m0 + ty) * K_DIM + k0 + tx];
        Bs[ty][tx] = W[(size_t)(n0 + ty) * K_DIM + k0 + tx];
        __syncthreads();
#pragma unroll
        for (int kk = 0; kk < 16; ++kk) acc += As[ty][kk] * Bs[tx][kk];
        __syncthreads();
    }
    out[(size_t)(m0 + ty) * N_DIM + n0 + tx] = acc + bias[n0 + tx];
}

// ---------------------------------------------------------------------------
extern "C" void kernel_launch(void* const* d_in, const int* in_sizes, int n_in,
                              void* d_out, int out_size, void* d_ws, size_t ws_size,
                              hipStream_t stream) {
    const float* X     = (const float*)d_in[0];  // [B,T,IN]  = [M,K]
    const float* Wt    = (const float*)d_in[1];  // [OUT,IN]  = [N,K]
    const float* bias  = (const float*)d_in[2];  // [OUT]
    const float* decay = (const float*)d_in[3];  // [OUT]
    float* out = (float*)d_out;                  // [B,T,OUT] = [M,N]

    // One-time opt-in for 128 KiB dynamic LDS (host-side, capture-safe).
    static bool big_lds_ok = [] {
        return hipFuncSetAttribute(reinterpret_cast<const void*>(gemm_8phase),
                                   hipFuncAttributeMaxDynamicSharedMemorySize,
                                   131072) == hipSuccess;
    }();

    const size_t A_bytes  = (size_t)M_DIM * K_DIM * 2;            // 64 MB
    const size_t W_bytes  = (size_t)N_DIM * K_DIM * 2;            // 2 MB
    const size_t C_bytes  = (size_t)M_DIM * N_DIM * 2;            // 64 MB
    const size_t cr_bytes = (size_t)B_DIM * NCHUNK * N_DIM * 4;   // 1 MB
    const size_t need_mid  = A_bytes + W_bytes;
    const size_t need_full = A_bytes + W_bytes + C_bytes + cr_bytes;

    if (ws_size >= need_full) {
        unsigned short* Abf = (unsigned short*)d_ws;
        unsigned short* Wbf = (unsigned short*)((char*)d_ws + A_bytes);
        unsigned short* Cbf = (unsigned short*)((char*)d_ws + A_bytes + W_bytes);
        float* carry = (float*)((char*)d_ws + A_bytes + W_bytes + C_bytes);
        cast_f32_bf16_x8<<<(M_DIM * K_DIM / 8 + 255) / 256, 256, 0, stream>>>(X, Abf, M_DIM * K_DIM / 8);
        cast_f32_bf16_x8<<<(N_DIM * K_DIM / 8 + 255) / 256, 256, 0, stream>>>(Wt, Wbf, N_DIM * K_DIM / 8);
        if (big_lds_ok) {
            gemm_8phase<<<dim3(4, 128), 512, 131072, stream>>>(Abf, Wbf, bias, Cbf);
        } else {
            gemm_mfma<<<dim3(N_DIM / 128, M_DIM / 128), 256, 0, stream>>>(Abf, Wbf, bias, Cbf, nullptr);
        }
        const int scan_threads = B_DIM * NCHUNK * N_DIM / 2;      // 131072
        scan_carry2<<<scan_threads / 256, 256, 0, stream>>>((const uint32*)Cbf, decay, carry);
        scan_apply2<<<scan_threads / 256, 256, 0, stream>>>((const uint32*)Cbf, decay, carry, out);
    } else if (ws_size >= need_mid) {
        unsigned short* Abf = (unsigned short*)d_ws;
        unsigned short* Wbf = (unsigned short*)((char*)d_ws + A_bytes);
        cast_f32_bf16_x8<<<(M_DIM * K_DIM / 8 + 255) / 256, 256, 0, stream>>>(X, Abf, M_DIM * K_DIM / 8);
        cast_f32_bf16_x8<<<(N_DIM * K_DIM / 8 + 255) / 256, 256, 0, stream>>>(Wt, Wbf, N_DIM * K_DIM / 8);
        gemm_mfma<<<dim3(N_DIM / 128, M_DIM / 128), 256, 0, stream>>>(Abf, Wbf, bias, nullptr, out);
        scan_f32_inplace<<<512, 64, 0, stream>>>(out, decay);
    } else {
        gemm_naive<<<dim3(N_DIM / 16, M_DIM / 16), dim3(16, 16), 0, stream>>>(X, Wt, bias, out);
        scan_f32_inplace<<<512, 64, 0, stream>>>(out, decay);
    }
}